// Round 1
// baseline (746.969 us; speedup 1.0000x reference)
//
#include <hip/hip_runtime.h>
#include <math.h>

#define RDIM 256
#define CIN 64
#define COUT 64
#define MODES 16
#define NB 8

// Build cos/sin table: tab[p] = (cos(2*pi*p/256), sin(2*pi*p/256))
__device__ __forceinline__ void build_tab(float2* tab) {
    for (int p = (int)threadIdx.x; p < 256; p += (int)blockDim.x) {
        float ang = (float)p * (float)(2.0 * M_PI / 256.0);
        float s, c;
        sincosf(ang, &s, &c);
        tab[p] = make_float2(c, s);
    }
}

// Kernel 1: partial forward DFT along y for ky = 0..15.
// A[((b*256+x)*16 + ky)*64 + i] = sum_y X[b,x,y,i] * e^{-2pi i ky y/256}
__global__ __launch_bounds__(256) void k_fwd_y(const float* __restrict__ X,
                                               float2* __restrict__ A) {
    __shared__ float2 tab[256];
    __shared__ float Xs[128 * 64];
    int b = blockIdx.x >> 8;
    int x = blockIdx.x & 255;
    build_tab(tab);
    int t = (int)threadIdx.x;
    int i = t & 63;
    int kg = t >> 6;  // 0..3
    float ar[4], ai[4];
#pragma unroll
    for (int j = 0; j < 4; j++) { ar[j] = 0.f; ai[j] = 0.f; }
    const float* Xrow = X + ((size_t)(b * 256 + x)) * 256 * 64;
    for (int h = 0; h < 2; h++) {
        __syncthreads();
        for (int e = t; e < 128 * 64; e += 256) Xs[e] = Xrow[h * 128 * 64 + e];
        __syncthreads();
        for (int yl = 0; yl < 128; yl++) {
            int y = h * 128 + yl;
            float xv = Xs[yl * 64 + i];
#pragma unroll
            for (int j = 0; j < 4; j++) {
                int ky = kg + 4 * j;
                int p = (ky * y) & 255;
                float2 cs = tab[p];
                ar[j] += xv * cs.x;   // cos
                ai[j] -= xv * cs.y;   // -sin
            }
        }
    }
    float2* Arow = A + ((size_t)(b * 256 + x)) * 16 * 64;
#pragma unroll
    for (int j = 0; j < 4; j++) {
        int ky = kg + 4 * j;
        Arow[ky * 64 + i] = make_float2(ar[j], ai[j]);
    }
}

// Kernel 2: per (b, ky): forward x-DFT (32 kept kx modes, with 1/256 ortho
// scale), complex channel mixing with fw0/fw1, inverse x-DFT to all 256 x.
// G[((b*256+x)*16 + ky)*64 + o]
__global__ __launch_bounds__(256) void k_modes(const float2* __restrict__ A,
                                               const float* __restrict__ fw0,
                                               const float* __restrict__ fw1,
                                               float2* __restrict__ G) {
    __shared__ float2 tab[256];
    __shared__ float2 cs_[32 * 64];
    __shared__ float2 ds_[32 * 64];
    int b = blockIdx.x >> 4;
    int ky = blockIdx.x & 15;
    build_tab(tab);
    __syncthreads();
    int t = (int)threadIdx.x;
    int lane = t & 63;
    int g = t >> 6;  // 0..3

    // Phase 1: forward x-DFT. thread: i = lane, modes m = g + 4*j (j=0..7)
    {
        int i = lane;
        float cr[8], ci[8];
        int kxv[8];
#pragma unroll
        for (int j = 0; j < 8; j++) {
            cr[j] = 0.f; ci[j] = 0.f;
            int m = g + 4 * j;
            kxv[j] = (m < 16) ? m : (m + 224);  // 240..255
        }
        const float2* Ap = A + ((size_t)b * 256) * 16 * 64 + ky * 64 + i;
        for (int x = 0; x < 256; x++) {
            float2 a = Ap[(size_t)x * 16 * 64];
#pragma unroll
            for (int j = 0; j < 8; j++) {
                int p = (kxv[j] * x) & 255;
                float2 tc = tab[p];
                // multiply by e^{-i th} = (c, -s)
                cr[j] += a.x * tc.x + a.y * tc.y;
                ci[j] += a.y * tc.x - a.x * tc.y;
            }
        }
        const float sc = 1.0f / 256.0f;  // forward ortho scale
#pragma unroll
        for (int j = 0; j < 8; j++) {
            int m = g + 4 * j;
            cs_[m * 64 + i] = make_float2(cr[j] * sc, ci[j] * sc);
        }
    }
    __syncthreads();

    // Phase 2: channel mix. thread: o = lane, modes m = g + 4*j
    {
        int o = lane;
#pragma unroll
        for (int j = 0; j < 8; j++) {
            int m = g + 4 * j;
            const float* w = (m < 16) ? fw0 : fw1;
            int mx = (m < 16) ? m : (m - 16);
            float dr = 0.f, di = 0.f;
            for (int i2 = 0; i2 < 64; i2++) {
                float2 c = cs_[m * 64 + i2];
                const float* wp = w + ((((size_t)i2 * 64 + o) * 16 + mx) * 16 + ky) * 2;
                float wr = wp[0], wi = wp[1];
                dr += c.x * wr - c.y * wi;
                di += c.x * wi + c.y * wr;
            }
            ds_[m * 64 + o] = make_float2(dr, di);
        }
    }
    __syncthreads();

    // Phase 3: inverse x-DFT to all x. thread: o = lane, x = g + 4*k
    {
        int o = lane;
        float2* Gp = G + ((size_t)b * 256) * 16 * 64 + ky * 64 + o;
        for (int k = 0; k < 64; k++) {
            int x = g + 4 * k;
            float gr = 0.f, gi = 0.f;
#pragma unroll
            for (int m = 0; m < 32; m++) {
                int kx = (m < 16) ? m : (m + 224);
                float2 d = ds_[m * 64 + o];
                int p = (kx * x) & 255;
                float2 tc = tab[p];
                // multiply by e^{+i th} = (c, s)
                gr += d.x * tc.x - d.y * tc.y;
                gi += d.x * tc.y + d.y * tc.x;
            }
            Gp[(size_t)x * 16 * 64] = make_float2(gr, gi);
        }
    }
}

// Kernel 3: inverse y-DFT (Hermitian fold, numpy irfft ignores imag of DC
// bin) + residual GEMM + bias + SiLU.
__global__ __launch_bounds__(256) void k_out(const float* __restrict__ X,
                                             const float2* __restrict__ G,
                                             const float* __restrict__ Wres,
                                             const float* __restrict__ bres,
                                             float* __restrict__ out) {
    __shared__ float2 tab[256];
    __shared__ float bs[64];
    __shared__ float2 Gs[16 * 64];
    __shared__ float Xs[128 * 64];
    int b = blockIdx.x >> 8;
    int x = blockIdx.x & 255;
    build_tab(tab);
    int t = (int)threadIdx.x;
    if (t < 64) bs[t] = bres[t];
    const float2* Gp = G + ((size_t)(b * 256 + x)) * 16 * 64;
    for (int e = t; e < 16 * 64; e += 256) Gs[e] = Gp[e];

    int o = t & 63;
    int yg = t >> 6;  // 0..3

    // W column for this thread's o, in registers (coalesced global reads)
    float wcol[64];
#pragma unroll
    for (int i2 = 0; i2 < 64; i2++) wcol[i2] = Wres[i2 * 64 + o];

    const float* Xrow = X + ((size_t)(b * 256 + x)) * 256 * 64;
    float* orow = out + ((size_t)(b * 256 + x)) * 256 * 64;

    for (int h = 0; h < 2; h++) {
        __syncthreads();
        for (int e = t; e < 128 * 64; e += 256) Xs[e] = Xrow[h * 128 * 64 + e];
        __syncthreads();
        for (int k = 0; k < 32; k++) {
            int yl = yg + 4 * k;
            int y = h * 128 + yl;
            // residual: X[y,:] . Wres[:,o]
            float acc = bs[o];
            const float4* Xq = (const float4*)(Xs + yl * 64);
#pragma unroll
            for (int q = 0; q < 16; q++) {
                float4 xv = Xq[q];
                acc += xv.x * wcol[4 * q + 0] + xv.y * wcol[4 * q + 1] +
                       xv.z * wcol[4 * q + 2] + xv.w * wcol[4 * q + 3];
            }
            // spectral inverse along y
            float xr = Gs[o].x;  // ky = 0 (imag of DC bin ignored by irfft)
#pragma unroll
            for (int ky = 1; ky < 16; ky++) {
                float2 gv = Gs[ky * 64 + o];
                int p = (ky * y) & 255;
                float2 tc = tab[p];
                xr += 2.0f * (gv.x * tc.x - gv.y * tc.y);
            }
            float v = xr * (1.0f / 256.0f) + acc;
            float sv = v / (1.0f + __expf(-v));
            orow[(size_t)y * 64 + o] = sv;
        }
    }
}

extern "C" void kernel_launch(void* const* d_in, const int* in_sizes, int n_in,
                              void* d_out, int out_size, void* d_ws, size_t ws_size,
                              hipStream_t stream) {
    const float* X    = (const float*)d_in[0];
    const float* Wres = (const float*)d_in[1];
    const float* bres = (const float*)d_in[2];
    const float* fw0  = (const float*)d_in[3];
    const float* fw1  = (const float*)d_in[4];
    float* out = (float*)d_out;

    float2* A = (float2*)d_ws;                        // [8*256, 16, 64] complex
    float2* G = A + (size_t)NB * 256 * 16 * 64;       // [8*256, 16, 64] complex

    k_fwd_y<<<NB * 256, 256, 0, stream>>>(X, A);
    k_modes<<<NB * MODES, 256, 0, stream>>>(A, fw0, fw1, G);
    k_out<<<NB * 256, 256, 0, stream>>>(X, G, Wres, bres, out);
}

// Round 2
// 728.696 us; speedup vs baseline: 1.0251x; 1.0251x over previous
//
#include <hip/hip_runtime.h>
#include <math.h>

#define RDIM 256
#define CIN 64
#define COUT 64
#define MODES 16
#define NB 8

// cos/sin table: tab[p] = (cos(2*pi*p/256), sin(2*pi*p/256))
__device__ __forceinline__ void build_tab(float2* tab) {
    for (int p = (int)threadIdx.x; p < 256; p += (int)blockDim.x) {
        float ang = (float)p * (float)(2.0 * M_PI / 256.0);
        float s, c;
        sincosf(ang, &s, &c);
        tab[p] = make_float2(c, s);
    }
}

// ---------------------------------------------------------------------------
// k_wt: transpose weights fw0/fw1 [i,o,mx,ky,2] -> WT[m(32)][ky(16)][i(64)][o(64)] float2
// reads scattered (L2/L3 absorbs), writes coalesced.
__global__ __launch_bounds__(256) void k_wt(const float* __restrict__ fw0,
                                            const float* __restrict__ fw1,
                                            float2* __restrict__ WT) {
    int g = blockIdx.x * 256 + threadIdx.x;  // [0, 32*16*64*64)
    int o = g & 63;
    int i = (g >> 6) & 63;
    int ky = (g >> 12) & 15;
    int m = g >> 16;           // 0..31
    const float* src = (m < 16) ? fw0 : fw1;
    int mx = m & 15;
    const float2* s2 = (const float2*)src;
    // float2 index into fw: (i*64+o)*256 + mx*16 + ky
    WT[g] = s2[(size_t)(i * 64 + o) * 256 + mx * 16 + ky];
}

// ---------------------------------------------------------------------------
// k_fwd_y: A[b,x,ky,i] = sum_y X[b,x,y,i] e^{-2pi i ky y/256}
// grid (b*256+x), 256 thr: ky = t>>4, iq = t&15 (i = 4*iq..4*iq+3)
__global__ __launch_bounds__(256) void k_fwd_y(const float* __restrict__ X,
                                               float2* __restrict__ A) {
    __shared__ float2 tab[256];
    build_tab(tab);
    __syncthreads();
    int b = blockIdx.x >> 8;
    int x = blockIdx.x & 255;
    int t = (int)threadIdx.x;
    int ky = t >> 4;
    int iq = t & 15;
    float ar0 = 0.f, ai0 = 0.f, ar1 = 0.f, ai1 = 0.f;
    float ar2 = 0.f, ai2 = 0.f, ar3 = 0.f, ai3 = 0.f;
    const float4* Xr = (const float4*)(X + ((size_t)(b * 256 + x)) * 256 * 64);
    int p = 0;
#pragma unroll 8
    for (int y = 0; y < 256; y++) {
        float4 xv = Xr[y * 16 + iq];
        float2 cs = tab[p];
        p = (p + ky) & 255;
        ar0 += xv.x * cs.x; ai0 -= xv.x * cs.y;
        ar1 += xv.y * cs.x; ai1 -= xv.y * cs.y;
        ar2 += xv.z * cs.x; ai2 -= xv.z * cs.y;
        ar3 += xv.w * cs.x; ai3 -= xv.w * cs.y;
    }
    float2* Aw = A + ((size_t)(b * 256 + x)) * 16 * 64 + ky * 64 + iq * 4;
    float4* Aw4 = (float4*)Aw;
    Aw4[0] = make_float4(ar0, ai0, ar1, ai1);
    Aw4[1] = make_float4(ar2, ai2, ar3, ai3);
}

// ---------------------------------------------------------------------------
// K2a: forward x-DFT. C[b,ky,m,i] = (1/256) sum_x A[b,x,ky,i] e^{-i 2pi kx x/256}
// grid (b,ky,mg): 8*16*4 = 512 blocks; m = mg*8 + j. 256 thr: i = t&63, xg = t>>6.
__global__ __launch_bounds__(256) void k_fwd_x(const float2* __restrict__ A,
                                               float2* __restrict__ C) {
    __shared__ float2 tab[256];
    __shared__ float2 red[4 * 8 * 64];
    int bi = blockIdx.x;
    int b = bi >> 6;
    int ky = (bi >> 2) & 15;
    int mg = bi & 3;
    build_tab(tab);
    __syncthreads();
    int t = (int)threadIdx.x;
    int i = t & 63;
    int xg = t >> 6;
    float cr[8], ci[8];
    int kxv[8];
#pragma unroll
    for (int j = 0; j < 8; j++) {
        cr[j] = 0.f; ci[j] = 0.f;
        int m = mg * 8 + j;
        kxv[j] = (m < 16) ? m : (m + 224);
    }
    const float2* Ap = A + ((size_t)b * 256) * 16 * 64 + ky * 64 + i;
    for (int x = xg; x < 256; x += 4) {
        float2 a = Ap[(size_t)x * 16 * 64];
#pragma unroll
        for (int j = 0; j < 8; j++) {
            int p = (kxv[j] * x) & 255;
            float2 tc = tab[p];
            cr[j] += a.x * tc.x + a.y * tc.y;   // * e^{-i th}
            ci[j] += a.y * tc.x - a.x * tc.y;
        }
    }
#pragma unroll
    for (int j = 0; j < 8; j++) red[(xg * 8 + j) * 64 + i] = make_float2(cr[j], ci[j]);
    __syncthreads();
    const float sc = 1.0f / 256.0f;
    for (int e = t; e < 8 * 64; e += 256) {
        int j = e >> 6;
        int ii = e & 63;
        float2 s = red[j * 64 + ii];
        float2 s1 = red[(8 + j) * 64 + ii];
        float2 s2 = red[(16 + j) * 64 + ii];
        float2 s3 = red[(24 + j) * 64 + ii];
        float rr = (s.x + s1.x) + (s2.x + s3.x);
        float im = (s.y + s1.y) + (s2.y + s3.y);
        int m = mg * 8 + j;
        C[(((size_t)b * 16 + ky) * 32 + m) * 64 + ii] = make_float2(rr * sc, im * sc);
    }
}

// ---------------------------------------------------------------------------
// K2b: channel mix. D[b,ky,m,o] = sum_i C[b,ky,m,i] * w[i,o] (complex)
// grid (ky,m) = 512 blocks; loops all 8 b with WT slab in LDS.
__global__ __launch_bounds__(256) void k_mix(const float2* __restrict__ C,
                                             const float2* __restrict__ WT,
                                             float2* __restrict__ D) {
    __shared__ float2 Ws[64 * 64];   // [i][o]
    __shared__ float2 Cs[8 * 64];    // [b][i]
    __shared__ float2 red[4 * 8 * 64];
    int bi = blockIdx.x;
    int ky = bi >> 5;
    int m = bi & 31;
    int t = (int)threadIdx.x;
    const float4* Wsrc = (const float4*)(WT + ((size_t)(m * 16 + ky)) * 4096);
    float4* Wd = (float4*)Ws;
    for (int e = t; e < 2048; e += 256) Wd[e] = Wsrc[e];
    for (int e = t; e < 512; e += 256) {
        int b = e >> 6;
        int i = e & 63;
        Cs[e] = C[(((size_t)b * 16 + ky) * 32 + m) * 64 + i];
    }
    __syncthreads();
    int o = t & 63;
    int ig = t >> 6;
    float dr[8], di[8];
#pragma unroll
    for (int b = 0; b < 8; b++) { dr[b] = 0.f; di[b] = 0.f; }
    for (int i2 = ig * 16; i2 < ig * 16 + 16; i2++) {
        float2 w = Ws[i2 * 64 + o];
#pragma unroll
        for (int b = 0; b < 8; b++) {
            float2 c = Cs[b * 64 + i2];
            dr[b] += c.x * w.x - c.y * w.y;
            di[b] += c.x * w.y + c.y * w.x;
        }
    }
#pragma unroll
    for (int b = 0; b < 8; b++) red[(ig * 8 + b) * 64 + o] = make_float2(dr[b], di[b]);
    __syncthreads();
    for (int e = t; e < 512; e += 256) {
        int b = e >> 6;
        int oo = e & 63;
        float2 s = red[b * 64 + oo];
        float2 s1 = red[(8 + b) * 64 + oo];
        float2 s2 = red[(16 + b) * 64 + oo];
        float2 s3 = red[(24 + b) * 64 + oo];
        D[(((size_t)b * 16 + ky) * 32 + m) * 64 + oo] =
            make_float2((s.x + s1.x) + (s2.x + s3.x), (s.y + s1.y) + (s2.y + s3.y));
    }
}

// ---------------------------------------------------------------------------
// K2c: inverse x-DFT. G[b,x,ky,o] = sum_m D[b,ky,m,o] e^{+i 2pi kx x/256}
// grid (b,ky,xc) = 8*16*8 = 1024 blocks (32 x each); 256 thr: o = t&63, xg = t>>6.
__global__ __launch_bounds__(256) void k_inv_x(const float2* __restrict__ D,
                                               float2* __restrict__ G) {
    __shared__ float2 tab[256];
    __shared__ float2 Ds[32 * 64];   // [m][o]
    int bi = blockIdx.x;
    int b = bi >> 7;
    int ky = (bi >> 3) & 15;
    int xc = bi & 7;
    build_tab(tab);
    int t = (int)threadIdx.x;
    const float4* Dsrc = (const float4*)(D + (((size_t)b * 16 + ky) * 32) * 64);
    float4* Dd = (float4*)Ds;
    for (int e = t; e < 1024; e += 256) Dd[e] = Dsrc[e];
    __syncthreads();
    int o = t & 63;
    int xg = t >> 6;
#pragma unroll
    for (int j = 0; j < 8; j++) {
        int x = xc * 32 + xg * 8 + j;
        float gr = 0.f, gi = 0.f;
#pragma unroll
        for (int m = 0; m < 32; m++) {
            int kx = (m < 16) ? m : (m + 224);
            int p = (kx * x) & 255;
            float2 tc = tab[p];
            float2 d = Ds[m * 64 + o];
            gr += d.x * tc.x - d.y * tc.y;   // * e^{+i th}
            gi += d.x * tc.y + d.y * tc.x;
        }
        G[((size_t)(b * 256 + x) * 16 + ky) * 64 + o] = make_float2(gr, gi);
    }
}

// ---------------------------------------------------------------------------
// k_out: inverse y-DFT (Hermitian fold) + residual GEMM + bias + SiLU.
__global__ __launch_bounds__(256) void k_out(const float* __restrict__ X,
                                             const float2* __restrict__ G,
                                             const float* __restrict__ Wres,
                                             const float* __restrict__ bres,
                                             float* __restrict__ out) {
    __shared__ float2 tab[256];
    __shared__ float bs[64];
    __shared__ float2 Gs[16 * 64];
    __shared__ float Xs[64 * 64];    // 16 KB chunk (64 y)
    int b = blockIdx.x >> 8;
    int x = blockIdx.x & 255;
    build_tab(tab);
    int t = (int)threadIdx.x;
    if (t < 64) bs[t] = bres[t];
    const float2* Gp = G + ((size_t)(b * 256 + x)) * 16 * 64;
    for (int e = t; e < 16 * 64; e += 256) {
        float2 g = Gp[e];
        int ky = e >> 6;
        float sc = (ky == 0) ? (1.0f / 256.0f) : (2.0f / 256.0f);
        Gs[e] = make_float2(g.x * sc, g.y * sc);
    }

    int o = t & 63;
    int yg = t >> 6;

    float wcol[64];
#pragma unroll
    for (int i2 = 0; i2 < 64; i2++) wcol[i2] = Wres[i2 * 64 + o];

    const float* Xrow = X + ((size_t)(b * 256 + x)) * 256 * 64;
    float* orow = out + ((size_t)(b * 256 + x)) * 256 * 64;

    for (int h = 0; h < 4; h++) {
        __syncthreads();
        {
            const float4* Xr4 = (const float4*)(Xrow + h * 64 * 64);
            float4* Xs4 = (float4*)Xs;
            for (int e = t; e < 1024; e += 256) Xs4[e] = Xr4[e];
        }
        __syncthreads();
        for (int k = 0; k < 16; k++) {
            int yl = k * 4 + yg;
            int y = h * 64 + yl;
            float acc = bs[o];
            const float4* Xq = (const float4*)(Xs + yl * 64);
#pragma unroll
            for (int q = 0; q < 16; q++) {
                float4 xv = Xq[q];
                acc += xv.x * wcol[4 * q + 0] + xv.y * wcol[4 * q + 1] +
                       xv.z * wcol[4 * q + 2] + xv.w * wcol[4 * q + 3];
            }
            float xr = Gs[o].x;  // ky=0: imag of DC bin ignored by irfft
#pragma unroll
            for (int ky = 1; ky < 16; ky++) {
                float2 gv = Gs[ky * 64 + o];
                int p = (ky * y) & 255;
                float2 tc = tab[p];
                xr += gv.x * tc.x - gv.y * tc.y;
            }
            float v = xr + acc;
            float sv = v / (1.0f + __expf(-v));
            orow[(size_t)y * 64 + o] = sv;
        }
    }
}

extern "C" void kernel_launch(void* const* d_in, const int* in_sizes, int n_in,
                              void* d_out, int out_size, void* d_ws, size_t ws_size,
                              hipStream_t stream) {
    const float* X    = (const float*)d_in[0];
    const float* Wres = (const float*)d_in[1];
    const float* bres = (const float*)d_in[2];
    const float* fw0  = (const float*)d_in[3];
    const float* fw1  = (const float*)d_in[4];
    float* out = (float*)d_out;

    // workspace layout (float2 units):
    // A/G : [8][256][16][64]          2,097,152
    // C   : [8][16][32][64]             262,144
    // D   : [8][16][32][64]             262,144
    // WT  : [32][16][64][64]          2,097,152
    float2* A  = (float2*)d_ws;
    float2* C  = A + 2097152;
    float2* D  = C + 262144;
    float2* WT = D + 262144;
    float2* G  = A;  // reuse A after k_fwd_x consumes it

    k_wt<<<8192, 256, 0, stream>>>(fw0, fw1, WT);
    k_fwd_y<<<NB * 256, 256, 0, stream>>>(X, A);
    k_fwd_x<<<NB * 16 * 4, 256, 0, stream>>>(A, C);
    k_mix<<<16 * 32, 256, 0, stream>>>(C, WT, D);
    k_inv_x<<<NB * 16 * 8, 256, 0, stream>>>(D, G);
    k_out<<<NB * 256, 256, 0, stream>>>(X, G, Wres, bres, out);
}

// Round 3
// 431.521 us; speedup vs baseline: 1.7310x; 1.6887x over previous
//
#include <hip/hip_runtime.h>
#include <math.h>

#define RDIM 256
#define CIN 64
#define COUT 64
#define MODES 16
#define NB 8

typedef short short8 __attribute__((ext_vector_type(8)));
typedef float f32x4 __attribute__((ext_vector_type(4)));

// f32 -> bf16 bits, round-to-nearest-even
__device__ __forceinline__ unsigned short f2b(float f) {
    unsigned u = __builtin_bit_cast(unsigned, f);
    unsigned r = (u + 0x7FFFu + ((u >> 16) & 1u)) >> 16;
    return (unsigned short)r;
}

// cos/sin table: tab[p] = (cos(2*pi*p/256), sin(2*pi*p/256))
__device__ __forceinline__ void build_tab(float2* tab) {
    for (int p = (int)threadIdx.x; p < 256; p += (int)blockDim.x) {
        float ang = (float)p * (float)(2.0 * M_PI / 256.0);
        float s, c;
        sincosf(ang, &s, &c);
        tab[p] = make_float2(c, s);
    }
}

// ---------------------------------------------------------------------------
// k_wt: transpose weights fw0/fw1 [i,o,mx,ky,2] -> WT[m(32)][ky(16)][i(64)][o(64)] float2
__global__ __launch_bounds__(256) void k_wt(const float* __restrict__ fw0,
                                            const float* __restrict__ fw1,
                                            float2* __restrict__ WT) {
    int g = blockIdx.x * 256 + threadIdx.x;
    int o = g & 63;
    int i = (g >> 6) & 63;
    int ky = (g >> 12) & 15;
    int m = g >> 16;
    const float* src = (m < 16) ? fw0 : fw1;
    int mx = m & 15;
    const float2* s2 = (const float2*)src;
    WT[g] = s2[(size_t)(i * 64 + o) * 256 + mx * 16 + ky];
}

// ---------------------------------------------------------------------------
// k_prep: WbT[o][k] = bf16(Wres[k][o]); Tg[y][kk] = bf16(kk&1 ? -sin : cos)
__global__ __launch_bounds__(256) void k_prep(const float* __restrict__ Wres,
                                              unsigned short* __restrict__ WbT,
                                              unsigned short* __restrict__ Tg) {
    int e = blockIdx.x * 256 + (int)threadIdx.x;  // [0, 12288)
    if (e < 4096) {
        int o = e >> 6, k = e & 63;
        WbT[o * 64 + k] = f2b(Wres[k * 64 + o]);
    } else {
        int f = e - 4096;  // [0, 8192)
        int y = f >> 5, kk = f & 31, ky = kk >> 1;
        int p = (ky * y) & 255;
        float ang = (float)p * (float)(2.0 * M_PI / 256.0);
        float s, c;
        sincosf(ang, &s, &c);
        Tg[f] = f2b((kk & 1) ? -s : c);
    }
}

// ---------------------------------------------------------------------------
// k_fwd_y: A[b,x,ky,i] = sum_y X[b,x,y,i] e^{-2pi i ky y/256}
__global__ __launch_bounds__(256) void k_fwd_y(const float* __restrict__ X,
                                               float2* __restrict__ A) {
    __shared__ float2 tab[256];
    build_tab(tab);
    __syncthreads();
    int b = blockIdx.x >> 8;
    int x = blockIdx.x & 255;
    int t = (int)threadIdx.x;
    int ky = t >> 4;
    int iq = t & 15;
    float ar0 = 0.f, ai0 = 0.f, ar1 = 0.f, ai1 = 0.f;
    float ar2 = 0.f, ai2 = 0.f, ar3 = 0.f, ai3 = 0.f;
    const float4* Xr = (const float4*)(X + ((size_t)(b * 256 + x)) * 256 * 64);
    int p = 0;
#pragma unroll 8
    for (int y = 0; y < 256; y++) {
        float4 xv = Xr[y * 16 + iq];
        float2 cs = tab[p];
        p = (p + ky) & 255;
        ar0 += xv.x * cs.x; ai0 -= xv.x * cs.y;
        ar1 += xv.y * cs.x; ai1 -= xv.y * cs.y;
        ar2 += xv.z * cs.x; ai2 -= xv.z * cs.y;
        ar3 += xv.w * cs.x; ai3 -= xv.w * cs.y;
    }
    float2* Aw = A + ((size_t)(b * 256 + x)) * 16 * 64 + ky * 64 + iq * 4;
    float4* Aw4 = (float4*)Aw;
    Aw4[0] = make_float4(ar0, ai0, ar1, ai1);
    Aw4[1] = make_float4(ar2, ai2, ar3, ai3);
}

// ---------------------------------------------------------------------------
// k_fwd_x: C[b,ky,m,i] = (1/256) sum_x A[b,x,ky,i] e^{-i 2pi kx x/256}
__global__ __launch_bounds__(256) void k_fwd_x(const float2* __restrict__ A,
                                               float2* __restrict__ C) {
    __shared__ float2 tab[256];
    __shared__ float2 red[4 * 8 * 64];
    int bi = blockIdx.x;
    int b = bi >> 6;
    int ky = (bi >> 2) & 15;
    int mg = bi & 3;
    build_tab(tab);
    __syncthreads();
    int t = (int)threadIdx.x;
    int i = t & 63;
    int xg = t >> 6;
    float cr[8], ci[8];
    int kxv[8];
#pragma unroll
    for (int j = 0; j < 8; j++) {
        cr[j] = 0.f; ci[j] = 0.f;
        int m = mg * 8 + j;
        kxv[j] = (m < 16) ? m : (m + 224);
    }
    const float2* Ap = A + ((size_t)b * 256) * 16 * 64 + ky * 64 + i;
    for (int x = xg; x < 256; x += 4) {
        float2 a = Ap[(size_t)x * 16 * 64];
#pragma unroll
        for (int j = 0; j < 8; j++) {
            int p = (kxv[j] * x) & 255;
            float2 tc = tab[p];
            cr[j] += a.x * tc.x + a.y * tc.y;
            ci[j] += a.y * tc.x - a.x * tc.y;
        }
    }
#pragma unroll
    for (int j = 0; j < 8; j++) red[(xg * 8 + j) * 64 + i] = make_float2(cr[j], ci[j]);
    __syncthreads();
    const float sc = 1.0f / 256.0f;
    for (int e = t; e < 8 * 64; e += 256) {
        int j = e >> 6;
        int ii = e & 63;
        float2 s = red[j * 64 + ii];
        float2 s1 = red[(8 + j) * 64 + ii];
        float2 s2 = red[(16 + j) * 64 + ii];
        float2 s3 = red[(24 + j) * 64 + ii];
        float rr = (s.x + s1.x) + (s2.x + s3.x);
        float im = (s.y + s1.y) + (s2.y + s3.y);
        int m = mg * 8 + j;
        C[(((size_t)b * 16 + ky) * 32 + m) * 64 + ii] = make_float2(rr * sc, im * sc);
    }
}

// ---------------------------------------------------------------------------
// k_mix: D[b,ky,m,o] = sum_i C[b,ky,m,i] * w[i,o] (complex)
__global__ __launch_bounds__(256) void k_mix(const float2* __restrict__ C,
                                             const float2* __restrict__ WT,
                                             float2* __restrict__ D) {
    __shared__ float2 Ws[64 * 64];
    __shared__ float2 Cs[8 * 64];
    __shared__ float2 red[4 * 8 * 64];
    int bi = blockIdx.x;
    int ky = bi >> 5;
    int m = bi & 31;
    int t = (int)threadIdx.x;
    const float4* Wsrc = (const float4*)(WT + ((size_t)(m * 16 + ky)) * 4096);
    float4* Wd = (float4*)Ws;
    for (int e = t; e < 2048; e += 256) Wd[e] = Wsrc[e];
    for (int e = t; e < 512; e += 256) {
        int b = e >> 6;
        int i = e & 63;
        Cs[e] = C[(((size_t)b * 16 + ky) * 32 + m) * 64 + i];
    }
    __syncthreads();
    int o = t & 63;
    int ig = t >> 6;
    float dr[8], di[8];
#pragma unroll
    for (int b = 0; b < 8; b++) { dr[b] = 0.f; di[b] = 0.f; }
    for (int i2 = ig * 16; i2 < ig * 16 + 16; i2++) {
        float2 w = Ws[i2 * 64 + o];
#pragma unroll
        for (int b = 0; b < 8; b++) {
            float2 c = Cs[b * 64 + i2];
            dr[b] += c.x * w.x - c.y * w.y;
            di[b] += c.x * w.y + c.y * w.x;
        }
    }
#pragma unroll
    for (int b = 0; b < 8; b++) red[(ig * 8 + b) * 64 + o] = make_float2(dr[b], di[b]);
    __syncthreads();
    for (int e = t; e < 512; e += 256) {
        int b = e >> 6;
        int oo = e & 63;
        float2 s = red[b * 64 + oo];
        float2 s1 = red[(8 + b) * 64 + oo];
        float2 s2 = red[(16 + b) * 64 + oo];
        float2 s3 = red[(24 + b) * 64 + oo];
        D[(((size_t)b * 16 + ky) * 32 + m) * 64 + oo] =
            make_float2((s.x + s1.x) + (s2.x + s3.x), (s.y + s1.y) + (s2.y + s3.y));
    }
}

// ---------------------------------------------------------------------------
// k_inv_x: G[b,x,ky,o] = sum_m D[b,ky,m,o] e^{+i 2pi kx x/256}
__global__ __launch_bounds__(256) void k_inv_x(const float2* __restrict__ D,
                                               float2* __restrict__ G) {
    __shared__ float2 tab[256];
    __shared__ float2 Ds[32 * 64];
    int bi = blockIdx.x;
    int b = bi >> 7;
    int ky = (bi >> 3) & 15;
    int xc = bi & 7;
    build_tab(tab);
    int t = (int)threadIdx.x;
    const float4* Dsrc = (const float4*)(D + (((size_t)b * 16 + ky) * 32) * 64);
    float4* Dd = (float4*)Ds;
    for (int e = t; e < 1024; e += 256) Dd[e] = Dsrc[e];
    __syncthreads();
    int o = t & 63;
    int xg = t >> 6;
#pragma unroll
    for (int j = 0; j < 8; j++) {
        int x = xc * 32 + xg * 8 + j;
        float gr = 0.f, gi = 0.f;
#pragma unroll
        for (int m = 0; m < 32; m++) {
            int kx = (m < 16) ? m : (m + 224);
            int p = (kx * x) & 255;
            float2 tc = tab[p];
            float2 d = Ds[m * 64 + o];
            gr += d.x * tc.x - d.y * tc.y;
            gi += d.x * tc.y + d.y * tc.x;
        }
        G[((size_t)(b * 256 + x) * 16 + ky) * 64 + o] = make_float2(gr, gi);
    }
}

// ---------------------------------------------------------------------------
// k_out: MFMA GEMM, K=96: out[y][o] = silu(X[y][:]Wres + T[y][:]Gfold + b)
// Block = (b,x). 4 waves; wave w owns y in [64w, 64w+64). A from global, B
// (Wres^T bf16, Gfold LDS). D-layout: row=(lane>>4)*4+reg, col=lane&15.
__global__ __launch_bounds__(256) void k_out(const float* __restrict__ X,
                                             const float2* __restrict__ G,
                                             const unsigned short* __restrict__ WbT,
                                             const unsigned short* __restrict__ Tg,
                                             const float* __restrict__ bres,
                                             float* __restrict__ out) {
    __shared__ unsigned short Bsp[64 * 32];  // Gfold^T: [o][kk]
    int b = blockIdx.x >> 8;
    int x = blockIdx.x & 255;
    int t = (int)threadIdx.x;

    // fold G row -> Bspec[kk][o] (stored transposed [o][kk]) with irfft scale
    const float2* Gp = G + ((size_t)(b * 256 + x)) * 16 * 64;
    for (int e = t; e < 1024; e += 256) {
        int ky = e >> 6, o = e & 63;
        float2 g = Gp[e];
        float sc = (ky == 0) ? (1.0f / 256.0f) : (2.0f / 256.0f);
        Bsp[o * 32 + 2 * ky]     = f2b(g.x * sc);
        Bsp[o * 32 + 2 * ky + 1] = f2b(g.y * sc);
    }
    __syncthreads();

    int w = t >> 6;
    int l = t & 63;
    int m16 = l & 15;
    int quad = l >> 4;

    // B-fragments: B[k][n], k = quad*8+j, n = 16*nt + m16
    short8 bw0[4], bw1[4], bs[4];
    float br[4];
#pragma unroll
    for (int nt = 0; nt < 4; nt++) {
        int o = nt * 16 + m16;
        bw0[nt] = *(const short8*)(WbT + o * 64 + quad * 8);
        bw1[nt] = *(const short8*)(WbT + o * 64 + 32 + quad * 8);
        bs[nt]  = *(const short8*)(Bsp + o * 32 + quad * 8);
        br[nt]  = bres[o];
    }

    const float* Xrow = X + ((size_t)(b * 256 + x)) * 256 * 64;
    float* orow = out + ((size_t)(b * 256 + x)) * 256 * 64;

    f32x4 acc[4][4];
#pragma unroll
    for (int mt = 0; mt < 4; mt++)
#pragma unroll
        for (int nt = 0; nt < 4; nt++) acc[mt][nt] = (f32x4){0.f, 0.f, 0.f, 0.f};

#pragma unroll
    for (int mt = 0; mt < 4; mt++) {
        int y = w * 64 + mt * 16 + m16;  // A-frag m index
        // A-frags from global: X (f32->bf16), T (bf16)
        const float4* xp = (const float4*)(Xrow + (size_t)y * 64 + quad * 8);
        float4 v0 = xp[0], v1 = xp[1];
        const float4* xq = (const float4*)(Xrow + (size_t)y * 64 + 32 + quad * 8);
        float4 v2 = xq[0], v3 = xq[1];
        short8 a0, a1;
        a0[0] = (short)f2b(v0.x); a0[1] = (short)f2b(v0.y);
        a0[2] = (short)f2b(v0.z); a0[3] = (short)f2b(v0.w);
        a0[4] = (short)f2b(v1.x); a0[5] = (short)f2b(v1.y);
        a0[6] = (short)f2b(v1.z); a0[7] = (short)f2b(v1.w);
        a1[0] = (short)f2b(v2.x); a1[1] = (short)f2b(v2.y);
        a1[2] = (short)f2b(v2.z); a1[3] = (short)f2b(v2.w);
        a1[4] = (short)f2b(v3.x); a1[5] = (short)f2b(v3.y);
        a1[6] = (short)f2b(v3.z); a1[7] = (short)f2b(v3.w);
        short8 aT = *(const short8*)(Tg + (size_t)y * 32 + quad * 8);
#pragma unroll
        for (int nt = 0; nt < 4; nt++) {
            acc[mt][nt] = __builtin_amdgcn_mfma_f32_16x16x32_bf16(a0, bw0[nt], acc[mt][nt], 0, 0, 0);
            acc[mt][nt] = __builtin_amdgcn_mfma_f32_16x16x32_bf16(a1, bw1[nt], acc[mt][nt], 0, 0, 0);
            acc[mt][nt] = __builtin_amdgcn_mfma_f32_16x16x32_bf16(aT, bs[nt],  acc[mt][nt], 0, 0, 0);
        }
    }

    // epilogue: bias + SiLU + store
#pragma unroll
    for (int mt = 0; mt < 4; mt++) {
#pragma unroll
        for (int nt = 0; nt < 4; nt++) {
            int o = nt * 16 + m16;
#pragma unroll
            for (int r = 0; r < 4; r++) {
                int y = w * 64 + mt * 16 + quad * 4 + r;
                float v = acc[mt][nt][r] + br[nt];
                orow[(size_t)y * 64 + o] = v / (1.0f + __expf(-v));
            }
        }
    }
}

extern "C" void kernel_launch(void* const* d_in, const int* in_sizes, int n_in,
                              void* d_out, int out_size, void* d_ws, size_t ws_size,
                              hipStream_t stream) {
    const float* X    = (const float*)d_in[0];
    const float* Wres = (const float*)d_in[1];
    const float* bres = (const float*)d_in[2];
    const float* fw0  = (const float*)d_in[3];
    const float* fw1  = (const float*)d_in[4];
    float* out = (float*)d_out;

    // workspace (float2 units): A/G 2097152 | C 262144 | D 262144 | WT 2097152
    float2* A  = (float2*)d_ws;
    float2* C  = A + 2097152;
    float2* D  = C + 262144;
    float2* WT = D + 262144;
    float2* G  = A;  // reuse A after k_fwd_x consumes it
    // WbT/Tg overlay the C region (free after k_mix): 4096 + 8192 ushorts = 24 KB
    unsigned short* WbT = (unsigned short*)C;
    unsigned short* Tg  = WbT + 4096;

    k_wt<<<8192, 256, 0, stream>>>(fw0, fw1, WT);
    k_fwd_y<<<NB * 256, 256, 0, stream>>>(X, A);
    k_fwd_x<<<NB * 16 * 4, 256, 0, stream>>>(A, C);
    k_mix<<<16 * 32, 256, 0, stream>>>(C, WT, D);
    k_prep<<<48, 256, 0, stream>>>(Wres, WbT, Tg);   // after k_mix (reuses C region)
    k_inv_x<<<NB * 16 * 8, 256, 0, stream>>>(D, G);
    k_out<<<NB * 256, 256, 0, stream>>>(X, G, WbT, Tg, bres, out);
}